// Round 5
// baseline (471.195 us; speedup 1.0000x reference)
//
#include <hip/hip_runtime.h>

#define TT 4096
#define BLK 256
#define WPB 4            // waves per block
#define CHUNKS 16        // TT / 256
#define EPSV 1e-8f

__device__ __forceinline__ float tf(int i) { return (float)i * 1e-3f; }

// One wave per trace. No LDS, no __syncthreads.
__global__ __launch_bounds__(BLK, 8) void w2_loss_kernel(
    const float* __restrict__ traces,
    const float* __restrict__ q_raw,
    float* __restrict__ part) {
  const int lane = threadIdx.x & 63;
  const int wid  = threadIdx.x >> 6;
  const long trace = (long)blockIdx.x * WPB + wid;
  const float* __restrict__ tr = traces + trace * TT;
  const float* __restrict__ qr = q_raw + trace * TT;
  const float4* __restrict__ tr4 = (const float4*)tr;

  // ---------- pass 1: streaming scan -> base[k] = chunk_prefix + lane_excl ----------
  float base[CHUNKS];
  float running = 0.0f;
  float4 cur = tr4[lane];  // chunk 0, coalesced 1KB per instruction
#pragma unroll
  for (int k = 0; k < CHUNKS; ++k) {
    float4 nxt = (k + 1 < CHUNKS) ? tr4[(k + 1) * 64 + lane]
                                  : make_float4(0.f, 0.f, 0.f, 0.f);
    float s0 = cur.x * cur.x + EPSV;
    float s1 = cur.y * cur.y + EPSV;
    float s2 = cur.z * cur.z + EPSV;
    float s3 = cur.w * cur.w + EPSV;
    float snx = nxt.x * nxt.x + EPSV;
    float nb = __shfl_down(s0, 1, 64);   // lane l <- lane l+1's s0
    float bc = __shfl(snx, 0, 64);       // next chunk's first s
    float s4 = (lane == 63) ? bc : nb;
    int e = k * 256 + lane * 4;
    float i0 = 0.5f * (s0 + s1) * (tf(e + 1) - tf(e));
    float i1 = 0.5f * (s1 + s2) * (tf(e + 2) - tf(e + 1));
    float i2 = 0.5f * (s2 + s3) * (tf(e + 3) - tf(e + 2));
    float i3 = (e + 3 < TT - 1) ? 0.5f * (s3 + s4) * (tf(e + 4) - tf(e + 3)) : 0.0f;
    float lt = i0 + i1 + i2 + i3;
    // inclusive wave scan of lane totals
    float v = lt;
#pragma unroll
    for (int off = 1; off < 64; off <<= 1) {
      float n = __shfl_up(v, off, 64);
      if (lane >= off) v += n;
    }
    base[k] = running + (v - lt);        // exclusive prefix for this lane's chunk slot
    running += __shfl(v, 63, 64);        // add chunk total
    cur = nxt;
  }
  const float inv_norm = 1.0f / running;  // running == norm

  // ---------- pass 2: re-read (L2-hot), cdf -> gather -> loss ----------
  float local = 0.0f;
  cur = tr4[lane];
#pragma unroll
  for (int k = 0; k < CHUNKS; ++k) {
    float4 nxt = (k + 1 < CHUNKS) ? tr4[(k + 1) * 64 + lane]
                                  : make_float4(0.f, 0.f, 0.f, 0.f);
    float s0 = cur.x * cur.x + EPSV;
    float s1 = cur.y * cur.y + EPSV;
    float s2 = cur.z * cur.z + EPSV;
    float s3 = cur.w * cur.w + EPSV;
    float snx = nxt.x * nxt.x + EPSV;
    float nb = __shfl_down(s0, 1, 64);
    float bc = __shfl(snx, 0, 64);
    float s4 = (lane == 63) ? bc : nb;
    int e = k * 256 + lane * 4;
    float i0 = 0.5f * (s0 + s1) * (tf(e + 1) - tf(e));
    float i1 = 0.5f * (s1 + s2) * (tf(e + 2) - tf(e + 1));
    float i2 = 0.5f * (s2 + s3) * (tf(e + 3) - tf(e + 2));
    // cdf (exclusive of own increment) per element
    float c[4];
    c[0] = base[k];
    c[1] = c[0] + i0;
    c[2] = c[1] + i1;
    c[3] = c[2] + i2;
    float sv[4] = {s0, s1, s2, s3};

    // compute all indices/fractions, then issue all 8 gather loads together
    int ix[4];
    float fr[4];
#pragma unroll
    for (int j = 0; j < 4; ++j) {
      float x = c[j] * inv_norm;
      float u = x * (float)(TT - 1);
      int i0i = (int)floorf(u);
      i0i = (i0i < 0) ? 0 : ((i0i > TT - 2) ? TT - 2 : i0i);
      float f = u - (float)i0i;
      ix[j] = i0i;
      fr[j] = fminf(fmaxf(f, 0.0f), 1.0f);
    }
    float q0v[4], q1v[4];
#pragma unroll
    for (int j = 0; j < 4; ++j) {
      q0v[j] = qr[ix[j]];
      q1v[j] = qr[ix[j] + 1];
    }
#pragma unroll
    for (int j = 0; j < 4; ++j) {
      float transport = q0v[j] + fr[j] * (q1v[j] - q0v[j]);
      int ei = e + j;
      float d = tf(ei) - transport;
      float tlo = tf((ei == 0) ? 0 : ei - 1);
      float thi = tf((ei == TT - 1) ? (TT - 1) : ei + 1);
      float w = 0.5f * (thi - tlo);
      local += d * d * sv[j] * w;
    }
    cur = nxt;
  }
  local *= inv_norm;

  // wave reduce -> one coalesced store per trace
#pragma unroll
  for (int off = 32; off > 0; off >>= 1) local += __shfl_down(local, off, 64);
  if (lane == 0) part[trace] = local;
}

__global__ __launch_bounds__(BLK) void reduce_kernel(
    const float* __restrict__ part, float* __restrict__ out, int n) {
  __shared__ float wave_red[4];
  const int tid = threadIdx.x;
  float local = 0.0f;
  for (int i = tid; i < n; i += BLK) local += part[i];
#pragma unroll
  for (int off = 32; off > 0; off >>= 1) local += __shfl_down(local, off, 64);
  if ((tid & 63) == 0) wave_red[tid >> 6] = local;
  __syncthreads();
  if (tid == 0) out[0] = wave_red[0] + wave_red[1] + wave_red[2] + wave_red[3];
}

extern "C" void kernel_launch(void* const* d_in, const int* in_sizes, int n_in,
                              void* d_out, int out_size, void* d_ws, size_t ws_size,
                              hipStream_t stream) {
  const float* traces = (const float*)d_in[0];
  const float* q_raw  = (const float*)d_in[3];
  float* out = (float*)d_out;
  float* part = (float*)d_ws;  // 8192 floats = 32 KB scratch

  const int n_traces = in_sizes[0] / TT;  // B*R = 8192
  w2_loss_kernel<<<n_traces / WPB, BLK, 0, stream>>>(traces, q_raw, part);
  reduce_kernel<<<1, BLK, 0, stream>>>(part, out, n_traces);
}

// Round 6
// 361.160 us; speedup vs baseline: 1.3047x; 1.3047x over previous
//
#include <hip/hip_runtime.h>

#define TT 4096
#define BLK 256
#define WPB 4            // waves per block
#define CHUNKS 16        // TT / 256
#define EPSV 1e-8f

__device__ __forceinline__ float tf(int i) { return (float)i * 1e-3f; }

// One wave per trace. No LDS, no __syncthreads.
// __launch_bounds__(256,4): ~128 VGPR budget. (256,8) forced 64 VGPRs and
// spilled ~850MB of scratch traffic per dispatch — never again.
__global__ __launch_bounds__(BLK, 4) void w2_loss_kernel(
    const float* __restrict__ traces,
    const float* __restrict__ q_raw,
    float* __restrict__ part) {
  const int lane = threadIdx.x & 63;
  const int wid  = threadIdx.x >> 6;
  const long trace = (long)blockIdx.x * WPB + wid;
  const float* __restrict__ tr = traces + trace * TT;
  const float* __restrict__ qr = q_raw + trace * TT;
  const float4* __restrict__ tr4 = (const float4*)tr;

  // ---------- pass 1: streaming scan -> base[k] = chunk_prefix + lane_excl ----------
  float base[CHUNKS];
  float running = 0.0f;
  float4 cur = tr4[lane];  // chunk 0, coalesced 1KB per instruction
#pragma unroll
  for (int k = 0; k < CHUNKS; ++k) {
    float4 nxt = (k + 1 < CHUNKS) ? tr4[(k + 1) * 64 + lane]
                                  : make_float4(0.f, 0.f, 0.f, 0.f);
    float s0 = cur.x * cur.x + EPSV;
    float s1 = cur.y * cur.y + EPSV;
    float s2 = cur.z * cur.z + EPSV;
    float s3 = cur.w * cur.w + EPSV;
    float snx = nxt.x * nxt.x + EPSV;
    float nb = __shfl_down(s0, 1, 64);   // lane l <- lane l+1's s0
    float bc = __shfl(snx, 0, 64);       // next chunk's first s
    float s4 = (lane == 63) ? bc : nb;
    int e = k * 256 + lane * 4;
    float i0 = 0.5f * (s0 + s1) * (tf(e + 1) - tf(e));
    float i1 = 0.5f * (s1 + s2) * (tf(e + 2) - tf(e + 1));
    float i2 = 0.5f * (s2 + s3) * (tf(e + 3) - tf(e + 2));
    float i3 = (e + 3 < TT - 1) ? 0.5f * (s3 + s4) * (tf(e + 4) - tf(e + 3)) : 0.0f;
    float lt = i0 + i1 + i2 + i3;
    // inclusive wave scan of lane totals
    float v = lt;
#pragma unroll
    for (int off = 1; off < 64; off <<= 1) {
      float n = __shfl_up(v, off, 64);
      if (lane >= off) v += n;
    }
    base[k] = running + (v - lt);        // exclusive prefix for this lane's chunk slot
    running += __shfl(v, 63, 64);        // add chunk total
    cur = nxt;
  }
  const float inv_norm = 1.0f / running;  // running == norm

  // ---------- pass 2: re-read (L2-hot), cdf -> gather -> loss ----------
  float local = 0.0f;
  cur = tr4[lane];
#pragma unroll
  for (int k = 0; k < CHUNKS; ++k) {
    float4 nxt = (k + 1 < CHUNKS) ? tr4[(k + 1) * 64 + lane]
                                  : make_float4(0.f, 0.f, 0.f, 0.f);
    float s0 = cur.x * cur.x + EPSV;
    float s1 = cur.y * cur.y + EPSV;
    float s2 = cur.z * cur.z + EPSV;
    float s3 = cur.w * cur.w + EPSV;
    float snx = nxt.x * nxt.x + EPSV;
    float nb = __shfl_down(s0, 1, 64);
    float bc = __shfl(snx, 0, 64);
    float s4 = (lane == 63) ? bc : nb;
    int e = k * 256 + lane * 4;
    float i0 = 0.5f * (s0 + s1) * (tf(e + 1) - tf(e));
    float i1 = 0.5f * (s1 + s2) * (tf(e + 2) - tf(e + 1));
    float i2 = 0.5f * (s2 + s3) * (tf(e + 3) - tf(e + 2));
    // cdf (exclusive of own increment) per element
    float c[4];
    c[0] = base[k];
    c[1] = c[0] + i0;
    c[2] = c[1] + i1;
    c[3] = c[2] + i2;
    float sv[4] = {s0, s1, s2, s3};

    // compute all indices/fractions, then issue all 8 gather loads together
    int ix[4];
    float fr[4];
#pragma unroll
    for (int j = 0; j < 4; ++j) {
      float x = c[j] * inv_norm;
      float u = x * (float)(TT - 1);
      int i0i = (int)floorf(u);
      i0i = (i0i < 0) ? 0 : ((i0i > TT - 2) ? TT - 2 : i0i);
      float f = u - (float)i0i;
      ix[j] = i0i;
      fr[j] = fminf(fmaxf(f, 0.0f), 1.0f);
    }
    float q0v[4], q1v[4];
#pragma unroll
    for (int j = 0; j < 4; ++j) {
      q0v[j] = qr[ix[j]];
      q1v[j] = qr[ix[j] + 1];
    }
#pragma unroll
    for (int j = 0; j < 4; ++j) {
      float transport = q0v[j] + fr[j] * (q1v[j] - q0v[j]);
      int ei = e + j;
      float d = tf(ei) - transport;
      float tlo = tf((ei == 0) ? 0 : ei - 1);
      float thi = tf((ei == TT - 1) ? (TT - 1) : ei + 1);
      float w = 0.5f * (thi - tlo);
      local += d * d * sv[j] * w;
    }
    cur = nxt;
  }
  local *= inv_norm;

  // wave reduce -> one coalesced store per trace
#pragma unroll
  for (int off = 32; off > 0; off >>= 1) local += __shfl_down(local, off, 64);
  if (lane == 0) part[trace] = local;
}

__global__ __launch_bounds__(BLK) void reduce_kernel(
    const float* __restrict__ part, float* __restrict__ out, int n) {
  __shared__ float wave_red[4];
  const int tid = threadIdx.x;
  float local = 0.0f;
  for (int i = tid; i < n; i += BLK) local += part[i];
#pragma unroll
  for (int off = 32; off > 0; off >>= 1) local += __shfl_down(local, off, 64);
  if ((tid & 63) == 0) wave_red[tid >> 6] = local;
  __syncthreads();
  if (tid == 0) out[0] = wave_red[0] + wave_red[1] + wave_red[2] + wave_red[3];
}

extern "C" void kernel_launch(void* const* d_in, const int* in_sizes, int n_in,
                              void* d_out, int out_size, void* d_ws, size_t ws_size,
                              hipStream_t stream) {
  const float* traces = (const float*)d_in[0];
  const float* q_raw  = (const float*)d_in[3];
  float* out = (float*)d_out;
  float* part = (float*)d_ws;  // 8192 floats = 32 KB scratch

  const int n_traces = in_sizes[0] / TT;  // B*R = 8192
  w2_loss_kernel<<<n_traces / WPB, BLK, 0, stream>>>(traces, q_raw, part);
  reduce_kernel<<<1, BLK, 0, stream>>>(part, out, n_traces);
}